// Round 2
// baseline (2379.322 us; speedup 1.0000x reference)
//
#include <hip/hip_runtime.h>

#define NN   102400
#define EE   819200
#define GG   512
#define NPG  200
#define HID  64
#define DD   128
#define TT   64
#define BB   8
#define HH   4
#define DHH  32
#define LL   4

typedef unsigned int uint;

static __device__ __forceinline__ float wave_sum64(float v) {
#pragma unroll
    for (int off = 32; off > 0; off >>= 1) v += __shfl_xor(v, off, 64);
    return v;
}

static __device__ __forceinline__ float block_sum128(float v, float* sm) {
    v = wave_sum64(v);
    int wid = threadIdx.x >> 6;
    if ((threadIdx.x & 63) == 0) sm[wid] = v;
    __syncthreads();
    float r = sm[0] + sm[1];
    __syncthreads();
    return r;
}

// ---------------- degree + edge bucketing ----------------

__global__ void k_deg_init(float* __restrict__ deg) {
    int i = blockIdx.x * blockDim.x + threadIdx.x;
    if (i < NN) deg[i] = 1.0f;  // self loop
}

__global__ void k_deg_scatter(const int* __restrict__ dst, float* __restrict__ deg) {
    int e = blockIdx.x * blockDim.x + threadIdx.x;
    if (e < EE) atomicAdd(&deg[dst[e]], 1.0f);
}

__global__ void k_ecount(const int* __restrict__ src, int* __restrict__ cnt) {
    int e = blockIdx.x * blockDim.x + threadIdx.x;
    if (e < EE) atomicAdd(&cnt[src[e] / NPG], 1);
}

__global__ void k_prefix(const int* __restrict__ cnt, int* __restrict__ off,
                         int* __restrict__ cursor) {
    __shared__ int sm[GG];
    int t = threadIdx.x;  // 512 threads, 1 block
    sm[t] = cnt[t];
    __syncthreads();
    for (int d = 1; d < GG; d <<= 1) {
        int v = (t >= d) ? sm[t - d] : 0;
        __syncthreads();
        sm[t] += v;
        __syncthreads();
    }
    int excl = (t == 0) ? 0 : sm[t - 1];
    off[t] = excl;
    cursor[t] = excl;
    if (t == GG - 1) off[GG] = sm[t];
}

__global__ void k_escatter(const int* __restrict__ src, const int* __restrict__ dst,
                           const float* __restrict__ deg, int* __restrict__ cursor,
                           uint* __restrict__ epack, float* __restrict__ esw) {
    int e = blockIdx.x * blockDim.x + threadIdx.x;
    if (e >= EE) return;
    int s = src[e], d = dst[e];
    int g = s / NPG;
    int pos = atomicAdd(&cursor[g], 1);
    epack[pos] = (uint)(s - g * NPG) | ((uint)(d - g * NPG) << 16);
    esw[pos] = rsqrtf(deg[s]) * rsqrtf(deg[d]);
}

// ---------------- GCN layers (LDS accumulator, one block per graph) ----------------

// layer 1: fused 2->64 transform + sym-norm agg + bias/relu/LN
__global__ __launch_bounds__(256) void k_gcn1(
    const float* __restrict__ x, const float* __restrict__ W,
    const float* __restrict__ deg, const int* __restrict__ off,
    const uint* __restrict__ epack, const float* __restrict__ esw,
    const float* __restrict__ gb, const float* __restrict__ lng,
    const float* __restrict__ lnb, float* __restrict__ hout) {
    int g = blockIdx.x;
    __shared__ float xs0[NPG], xs1[NPG], dinv2[NPG];
    __shared__ float out[NPG * 64];
    int tid = threadIdx.x;
    int j = tid & 63;
    float w0 = W[j], w1 = W[64 + j];
    for (int i = tid; i < NPG; i += 256) {
        xs0[i] = x[(g * NPG + i) * 2];
        xs1[i] = x[(g * NPG + i) * 2 + 1];
        dinv2[i] = 1.f / deg[g * NPG + i];
    }
    __syncthreads();
    // self-loop init
    for (int i = tid >> 6; i < NPG; i += 4)
        out[i * 64 + j] = (xs0[i] * w0 + xs1[i] * w1) * dinv2[i];
    __syncthreads();
    int e1 = off[g + 1];
    for (int e = off[g] + (tid >> 6); e < e1; e += 4) {
        uint pk = epack[e];
        float w = esw[e];
        int ls = pk & 0xffff, ld = pk >> 16;
        atomicAdd(&out[ld * 64 + j], (xs0[ls] * w0 + xs1[ls] * w1) * w);
    }
    __syncthreads();
    // bias + relu + LN (wave per node)
    for (int i = tid >> 6; i < NPG; i += 4) {
        float u = fmaxf(out[i * 64 + j] + gb[j], 0.f);
        float mean = wave_sum64(u) * (1.f / 64.f);
        float d = u - mean;
        float var = wave_sum64(d * d) * (1.f / 64.f);
        hout[(g * NPG + i) * 64 + j] = d * rsqrtf(var + 1e-5f) * lng[j] + lnb[j];
    }
}

// layer 2: gather pre-transformed t (64-wide) from global, agg in LDS, LN
__global__ __launch_bounds__(256) void k_gcn2(
    const float* __restrict__ t, const float* __restrict__ deg,
    const int* __restrict__ off, const uint* __restrict__ epack,
    const float* __restrict__ esw, const float* __restrict__ gb,
    const float* __restrict__ lng, const float* __restrict__ lnb,
    float* __restrict__ hout) {
    int g = blockIdx.x;
    __shared__ float dinv2[NPG];
    __shared__ float out[NPG * 64];
    int tid = threadIdx.x;
    int j = tid & 63;
    const float* tg = t + (size_t)g * NPG * 64;
    for (int i = tid; i < NPG; i += 256) dinv2[i] = 1.f / deg[g * NPG + i];
    __syncthreads();
    for (int i = tid >> 6; i < NPG; i += 4)
        out[i * 64 + j] = tg[i * 64 + j] * dinv2[i];
    __syncthreads();
    int e1 = off[g + 1];
    for (int e = off[g] + (tid >> 6); e < e1; e += 4) {
        uint pk = epack[e];
        float w = esw[e];
        int ls = pk & 0xffff, ld = pk >> 16;
        atomicAdd(&out[ld * 64 + j], tg[ls * 64 + j] * w);
    }
    __syncthreads();
    for (int i = tid >> 6; i < NPG; i += 4) {
        float u = fmaxf(out[i * 64 + j] + gb[j], 0.f);
        float mean = wave_sum64(u) * (1.f / 64.f);
        float d = u - mean;
        float var = wave_sum64(d * d) * (1.f / 64.f);
        hout[(g * NPG + i) * 64 + j] = d * rsqrtf(var + 1e-5f) * lng[j] + lnb[j];
    }
}

// layer 3 (128-wide, 2 slice-blocks per graph) + fused mean-readout + gb3 + PE
__global__ __launch_bounds__(256) void k_gcn3(
    const float* __restrict__ t, const float* __restrict__ deg,
    const int* __restrict__ off, const uint* __restrict__ epack,
    const float* __restrict__ esw, const float* __restrict__ b3,
    float* __restrict__ seq) {
    int g = blockIdx.x >> 1, sl = blockIdx.x & 1;
    __shared__ float dinv2[NPG];
    __shared__ float out[NPG * 64];
    __shared__ float red[4][64];
    int tid = threadIdx.x;
    int j = tid & 63;
    const float* tg = t + (size_t)g * NPG * DD + sl * 64;
    for (int i = tid; i < NPG; i += 256) dinv2[i] = 1.f / deg[g * NPG + i];
    __syncthreads();
    for (int i = tid >> 6; i < NPG; i += 4)
        out[i * 64 + j] = tg[i * DD + j] * dinv2[i];
    __syncthreads();
    int e1 = off[g + 1];
    for (int e = off[g] + (tid >> 6); e < e1; e += 4) {
        uint pk = epack[e];
        float w = esw[e];
        int ls = pk & 0xffff, ld = pk >> 16;
        atomicAdd(&out[ld * 64 + j], tg[ls * DD + j] * w);
    }
    __syncthreads();
    float s = 0.f;
    for (int i = tid >> 6; i < NPG; i += 4) s += out[i * 64 + j];
    red[tid >> 6][j] = s;
    __syncthreads();
    if (tid < 64) {
        int d = sl * 64 + j;
        float val = (red[0][j] + red[1][j] + red[2][j] + red[3][j]) * (1.f / NPG) + b3[d];
        float freq = expf((float)(d & ~1) * (-9.210340371976184f / 128.f));
        float ang = (float)(g & (TT - 1)) * freq;
        val += (d & 1) ? cosf(ang) : sinf(ang);
        seq[g * DD + d] = val;
    }
}

// dense per-node transform
template <int IN, int OUT>
__global__ void k_lin(const float* __restrict__ in, const float* __restrict__ W,
                      float* __restrict__ out) {
    int idx = blockIdx.x * blockDim.x + threadIdx.x;  // NN*OUT
    int n = idx / OUT, j = idx % OUT;
    if (n >= NN) return;
    const float* row = in + (long)n * IN;
    float acc = 0.f;
#pragma unroll 8
    for (int i = 0; i < IN; i++) acc += row[i] * W[i * OUT + j];
    out[idx] = acc;
}

// ---------------- Transformer ----------------

__global__ void k_qkv(const float* __restrict__ seq, const float* __restrict__ W,
                      const float* __restrict__ b, float* __restrict__ qkv) {
    int m = blockIdx.x, t = threadIdx.x;  // 512 x 128
    __shared__ float row[DD];
    row[t] = seq[m * DD + t];
    __syncthreads();
    for (int o = t; o < 384; o += 128) {
        float acc = b[o];
        const float* wr = W + o * DD;
#pragma unroll 8
        for (int d = 0; d < DD; d++) acc += row[d] * wr[d];
        qkv[m * 384 + o] = acc;
    }
}

__global__ void k_attn(const float* __restrict__ qkv, float* __restrict__ abuf) {
    int b = blockIdx.x >> 2, h = blockIdx.x & 3;  // 32 blocks x 64
    __shared__ float K[TT][DHH], V[TT][DHH];
    int t = threadIdx.x;
    for (int idx = t; idx < TT * DHH; idx += 64) {
        int j = idx >> 5, d = idx & 31;
        K[j][d] = qkv[(b * TT + j) * 384 + 128 + h * DHH + d];
        V[j][d] = qkv[(b * TT + j) * 384 + 256 + h * DHH + d];
    }
    __syncthreads();
    float q[DHH];
    const float* qp = qkv + (b * TT + t) * 384 + h * DHH;
#pragma unroll
    for (int d = 0; d < DHH; d++) q[d] = qp[d];
    const float scale = 0.17677669529663687f;  // 1/sqrt(32)
    float sc[TT];
    float mx = -1e30f;
    for (int j = 0; j < TT; j++) {
        float a = 0.f;
#pragma unroll
        for (int d = 0; d < DHH; d++) a += q[d] * K[j][d];
        a *= scale;
        sc[j] = a;
        mx = fmaxf(mx, a);
    }
    float ssum = 0.f;
    for (int j = 0; j < TT; j++) { sc[j] = expf(sc[j] - mx); ssum += sc[j]; }
    float inv = 1.f / ssum;
    float* op = abuf + (b * TT + t) * DD + h * DHH;
    for (int d = 0; d < DHH; d++) {
        float a = 0.f;
        for (int j = 0; j < TT; j++) a += sc[j] * V[j][d];
        op[d] = a * inv;
    }
}

__global__ void k_proj_res_ln(float* __restrict__ seq, const float* __restrict__ abuf,
                              const float* __restrict__ Wo, const float* __restrict__ bo,
                              const float* __restrict__ g, const float* __restrict__ bl) {
    int m = blockIdx.x, d = threadIdx.x;  // 512 x 128
    __shared__ float row[DD];
    __shared__ float sm[2];
    row[d] = abuf[m * DD + d];
    __syncthreads();
    float acc = bo[d];
    const float* wr = Wo + d * DD;
#pragma unroll 8
    for (int k = 0; k < DD; k++) acc += row[k] * wr[k];
    float u = seq[m * DD + d] + acc;
    float mean = block_sum128(u, sm) * (1.f / 128.f);
    float dv = u - mean;
    float var = block_sum128(dv * dv, sm) * (1.f / 128.f);
    seq[m * DD + d] = dv * rsqrtf(var + 1e-5f) * g[d] + bl[d];
}

__global__ void k_ffn1(const float* __restrict__ seq, const float* __restrict__ W,
                       const float* __restrict__ b, float* __restrict__ f1) {
    int m = blockIdx.x, t = threadIdx.x;  // 512 x 128
    __shared__ float row[DD];
    row[t] = seq[m * DD + t];
    __syncthreads();
    for (int k = t; k < 512; k += 128) {
        float acc = b[k];
        const float* wr = W + k * DD;
#pragma unroll 8
        for (int d = 0; d < DD; d++) acc += row[d] * wr[d];
        f1[m * 512 + k] = fmaxf(acc, 0.f);
    }
}

__global__ void k_ffn2_res_ln(float* __restrict__ seq, const float* __restrict__ f1,
                              const float* __restrict__ W, const float* __restrict__ b,
                              const float* __restrict__ g, const float* __restrict__ bl) {
    int m = blockIdx.x, d = threadIdx.x;  // 512 x 128
    __shared__ float row[512];
    __shared__ float sm[2];
    for (int i = d; i < 512; i += 128) row[i] = f1[m * 512 + i];
    __syncthreads();
    float acc = b[d];
    const float* wr = W + d * 512;
#pragma unroll 8
    for (int k = 0; k < 512; k++) acc += row[k] * wr[k];
    float u = seq[m * DD + d] + acc;
    float mean = block_sum128(u, sm) * (1.f / 128.f);
    float dv = u - mean;
    float var = block_sum128(dv * dv, sm) * (1.f / 128.f);
    seq[m * DD + d] = dv * rsqrtf(var + 1e-5f) * g[d] + bl[d];
}

__global__ void k_head(const float* __restrict__ seq, const float* __restrict__ W1,
                       const float* __restrict__ b1, const float* __restrict__ W2,
                       const float* __restrict__ b2, float* __restrict__ out) {
    int b = blockIdx.x, t = threadIdx.x;  // 8 x 128
    __shared__ float pooled[DD];
    __shared__ float hid[64];
    float s = 0.f;
    for (int i = 0; i < TT; i++) s += seq[(b * TT + i) * DD + t];
    pooled[t] = s * (1.f / TT);
    __syncthreads();
    if (t < 64) {
        float a = b1[t];
        const float* wr = W1 + t * DD;
        for (int k = 0; k < DD; k++) a += pooled[k] * wr[k];
        hid[t] = fmaxf(a, 0.f);
    }
    __syncthreads();
    if (t < 2) {
        float a = b2[t];
        const float* wr = W2 + t * 64;
        for (int k = 0; k < 64; k++) a += hid[k] * wr[k];
        out[b * 2 + t] = a;
    }
}

// ---------------- host ----------------

extern "C" void kernel_launch(void* const* d_in, const int* in_sizes, int n_in,
                              void* d_out, int out_size, void* d_ws, size_t ws_size,
                              hipStream_t stream) {
    const float* x     = (const float*)d_in[0];
    const int*   esrc  = (const int*)d_in[1];
    const int*   edst  = (const int*)d_in[2];
    const float* gW1   = (const float*)d_in[4];
    const float* gb1   = (const float*)d_in[5];
    const float* ln1g  = (const float*)d_in[6];
    const float* ln1b  = (const float*)d_in[7];
    const float* gW2   = (const float*)d_in[8];
    const float* gb2   = (const float*)d_in[9];
    const float* ln2g  = (const float*)d_in[10];
    const float* ln2b  = (const float*)d_in[11];
    const float* gW3   = (const float*)d_in[12];
    const float* gb3   = (const float*)d_in[13];
    const float* tWqkv = (const float*)d_in[14];
    const float* tbqkv = (const float*)d_in[15];
    const float* tWo   = (const float*)d_in[16];
    const float* tbo   = (const float*)d_in[17];
    const float* tg1   = (const float*)d_in[18];
    const float* tb1   = (const float*)d_in[19];
    const float* tg2   = (const float*)d_in[20];
    const float* tb2   = (const float*)d_in[21];
    const float* tWf1  = (const float*)d_in[22];
    const float* tbf1  = (const float*)d_in[23];
    const float* tWf2  = (const float*)d_in[24];
    const float* tbf2  = (const float*)d_in[25];
    const float* hW1   = (const float*)d_in[26];
    const float* hb1   = (const float*)d_in[27];
    const float* hW2   = (const float*)d_in[28];
    const float* hb2   = (const float*)d_in[29];
    float* out = (float*)d_out;

    float* p = (float*)d_ws;
    float* deg   = p; p += NN;
    float* esw   = p; p += EE;
    uint*  epack = (uint*)p; p += EE;
    int*   cnt    = (int*)p; p += GG;
    int*   off    = (int*)p; p += GG + 1;
    int*   cursor = (int*)p; p += GG + 3;  // keep 16B alignment
    float* bufA = p; p += (size_t)NN * 64;   // h1, h2
    float* bufB = p; p += (size_t)NN * DD;   // t2 (first half), t3
    float* seq  = p; p += GG * DD;
    float* qkv  = p; p += GG * 384;
    float* abuf = p; p += GG * DD;
    float* f1b  = p; p += GG * 512;

    const int BS = 256;
    // degrees
    k_deg_init<<<(NN + BS - 1) / BS, BS, 0, stream>>>(deg);
    k_deg_scatter<<<(EE + BS - 1) / BS, BS, 0, stream>>>(edst, deg);
    // bucket edges by graph (counting sort), fused norm-weight computation
    hipMemsetAsync(cnt, 0, GG * sizeof(int), stream);
    k_ecount<<<(EE + BS - 1) / BS, BS, 0, stream>>>(esrc, cnt);
    k_prefix<<<1, GG, 0, stream>>>(cnt, off, cursor);
    k_escatter<<<(EE + BS - 1) / BS, BS, 0, stream>>>(esrc, edst, deg, cursor, epack, esw);

    // GCN layer 1 (fused transform+agg+LN)
    k_gcn1<<<GG, BS, 0, stream>>>(x, gW1, deg, off, epack, esw, gb1, ln1g, ln1b, bufA);
    // GCN layer 2
    k_lin<64, 64><<<(NN * 64) / BS, BS, 0, stream>>>(bufA, gW2, bufB);
    k_gcn2<<<GG, BS, 0, stream>>>(bufB, deg, off, epack, esw, gb2, ln2g, ln2b, bufA);
    // GCN layer 3 + readout + PE
    k_lin<64, 128><<<(NN * 128) / BS, BS, 0, stream>>>(bufA, gW3, bufB);
    k_gcn3<<<GG * 2, BS, 0, stream>>>(bufB, deg, off, epack, esw, gb3, seq);

    // transformer layers
    for (int l = 0; l < LL; l++) {
        k_qkv<<<GG, DD, 0, stream>>>(seq, tWqkv + (size_t)l * 384 * 128, tbqkv + l * 384, qkv);
        k_attn<<<BB * HH, TT, 0, stream>>>(qkv, abuf);
        k_proj_res_ln<<<GG, DD, 0, stream>>>(seq, abuf, tWo + (size_t)l * 128 * 128,
                                             tbo + l * 128, tg1 + l * 128, tb1 + l * 128);
        k_ffn1<<<GG, DD, 0, stream>>>(seq, tWf1 + (size_t)l * 512 * 128, tbf1 + l * 512, f1b);
        k_ffn2_res_ln<<<GG, DD, 0, stream>>>(seq, f1b, tWf2 + (size_t)l * 128 * 512,
                                             tbf2 + l * 128, tg2 + l * 128, tb2 + l * 128);
    }

    // head
    k_head<<<BB, DD, 0, stream>>>(seq, hW1, hb1, hW2, hb2, out);
}

// Round 3
// 998.326 us; speedup vs baseline: 2.3833x; 2.3833x over previous
//
#include <hip/hip_runtime.h>

#define NN   102400
#define EE   819200
#define GG   512
#define NPG  200
#define DD   128
#define TT   64
#define BB   8
#define LL   4
#define ECAP 2304

typedef unsigned int uint;

static __device__ __forceinline__ float wave_sum64(float v) {
#pragma unroll
    for (int off = 32; off > 0; off >>= 1) v += __shfl_xor(v, off, 64);
    return v;
}

// ---------------- CSR build (sort edges by dst node) ----------------

__global__ void k_ncount(const int* __restrict__ dst, int* __restrict__ cnt) {
    int e = blockIdx.x * blockDim.x + threadIdx.x;
    if (e < EE) atomicAdd(&cnt[dst[e]], 1);
}

__global__ __launch_bounds__(64) void k_gsum(const int* __restrict__ cnt,
                                             int* __restrict__ gcnt) {
    int g = blockIdx.x, t = threadIdx.x;
    int s = 0;
    for (int i = t; i < NPG; i += 64) s += cnt[g * NPG + i];
#pragma unroll
    for (int off = 32; off > 0; off >>= 1) s += __shfl_xor(s, off, 64);
    if (t == 0) gcnt[g] = s;
}

__global__ void k_gprefix(const int* __restrict__ gcnt, int* __restrict__ gbase) {
    __shared__ int sm[GG];
    int t = threadIdx.x;
    int c = gcnt[t];
    sm[t] = c;
    __syncthreads();
    for (int d = 1; d < GG; d <<= 1) {
        int v = (t >= d) ? sm[t - d] : 0;
        __syncthreads();
        sm[t] += v;
        __syncthreads();
    }
    gbase[t] = sm[t] - c;
    if (t == GG - 1) gbase[GG] = sm[t];
}

__global__ __launch_bounds__(256) void k_nscan(const int* __restrict__ cnt,
                                               const int* __restrict__ gbase,
                                               int* __restrict__ node_off,
                                               int* __restrict__ cursorN) {
    int g = blockIdx.x, t = threadIdx.x;
    __shared__ int sm[256];
    int c = (t < NPG) ? cnt[g * NPG + t] : 0;
    sm[t] = c;
    __syncthreads();
    for (int d = 1; d < 256; d <<= 1) {
        int v = (t >= d) ? sm[t - d] : 0;
        __syncthreads();
        sm[t] += v;
        __syncthreads();
    }
    if (t < NPG) {
        int off = gbase[g] + sm[t] - c;
        node_off[g * NPG + t] = off;
        cursorN[g * NPG + t] = off;
    }
    if (g == GG - 1 && t == 0) node_off[NN] = gbase[GG];
}

__global__ void k_escatter(const int* __restrict__ src, const int* __restrict__ dst,
                           const int* __restrict__ cnt, int* __restrict__ cursorN,
                           uint2* __restrict__ epackN) {
    int e = blockIdx.x * blockDim.x + threadIdx.x;
    if (e >= EE) return;
    int s = src[e], d = dst[e];
    int pos = atomicAdd(&cursorN[d], 1);
    float w = rsqrtf((float)(cnt[s] + 1)) * rsqrtf((float)(cnt[d] + 1));
    epackN[pos] = make_uint2((uint)(s % NPG), __float_as_uint(w));
}

// ---------------- GCN layers: CSR + LDS source staging, register acc ----------------

__global__ __launch_bounds__(256) void k_gcn1(
    const float* __restrict__ x, const float* __restrict__ W,
    const int* __restrict__ cnt, const int* __restrict__ node_off,
    const uint2* __restrict__ epackN, const float* __restrict__ gb,
    const float* __restrict__ lng, const float* __restrict__ lnb,
    float* __restrict__ hout) {
    int g = blockIdx.x;
    __shared__ float2 xs[NPG];
    __shared__ float dinv2[NPG];
    __shared__ int noff[NPG + 1];
    __shared__ uint2 eb[ECAP];
    int tid = threadIdx.x, j = tid & 63, wid = tid >> 6;
    for (int i = tid; i <= NPG; i += 256) noff[i] = node_off[g * NPG + i];
    for (int i = tid; i < NPG; i += 256) {
        xs[i] = ((const float2*)x)[g * NPG + i];
        dinv2[i] = 1.f / (float)(cnt[g * NPG + i] + 1);
    }
    __syncthreads();
    int ebase = noff[0];
    int ecnt = noff[NPG] - ebase;
    const uint2* eg = epackN + ebase;
    int ecap = ecnt < ECAP ? ecnt : ECAP;
    for (int i = tid; i < ecap; i += 256) eb[i] = eg[i];
    __syncthreads();
    float w0 = W[j], w1 = W[64 + j];
    for (int i = wid; i < NPG; i += 4) {
        float2 xv = xs[i];
        float acc = (xv.x * w0 + xv.y * w1) * dinv2[i];
        int e0 = noff[i] - ebase, e1 = noff[i + 1] - ebase;
        int eC = e1 < ECAP ? e1 : ECAP;
        for (int e = e0; e < eC; ++e) {
            uint2 ed = eb[e];
            float2 xe = xs[ed.x];
            acc += (xe.x * w0 + xe.y * w1) * __uint_as_float(ed.y);
        }
        for (int e = e0 > ECAP ? e0 : ECAP; e < e1; ++e) {
            uint2 ed = eg[e];
            float2 xe = xs[ed.x];
            acc += (xe.x * w0 + xe.y * w1) * __uint_as_float(ed.y);
        }
        float u = fmaxf(acc + gb[j], 0.f);
        float mean = wave_sum64(u) * (1.f / 64.f);
        float dv = u - mean;
        float var = wave_sum64(dv * dv) * (1.f / 64.f);
        hout[(g * NPG + i) * 64 + j] = dv * rsqrtf(var + 1e-5f) * lng[j] + lnb[j];
    }
}

__global__ __launch_bounds__(256) void k_gcn2(
    const float* __restrict__ tg_all, const int* __restrict__ cnt,
    const int* __restrict__ node_off, const uint2* __restrict__ epackN,
    const float* __restrict__ gb, const float* __restrict__ lng,
    const float* __restrict__ lnb, float* __restrict__ hout) {
    int g = blockIdx.x;
    __shared__ float ts[NPG * 64];
    __shared__ float dinv2[NPG];
    __shared__ int noff[NPG + 1];
    __shared__ uint2 eb[ECAP];
    int tid = threadIdx.x, j = tid & 63, wid = tid >> 6;
    const float4* tg4 = (const float4*)(tg_all + (size_t)g * NPG * 64);
    float4* ts4 = (float4*)ts;
    for (int i = tid; i < NPG * 16; i += 256) ts4[i] = tg4[i];
    for (int i = tid; i <= NPG; i += 256) noff[i] = node_off[g * NPG + i];
    for (int i = tid; i < NPG; i += 256) dinv2[i] = 1.f / (float)(cnt[g * NPG + i] + 1);
    __syncthreads();
    int ebase = noff[0];
    int ecnt = noff[NPG] - ebase;
    const uint2* eg = epackN + ebase;
    int ecap = ecnt < ECAP ? ecnt : ECAP;
    for (int i = tid; i < ecap; i += 256) eb[i] = eg[i];
    __syncthreads();
    for (int i = wid; i < NPG; i += 4) {
        float acc = ts[i * 64 + j] * dinv2[i];
        int e0 = noff[i] - ebase, e1 = noff[i + 1] - ebase;
        int eC = e1 < ECAP ? e1 : ECAP;
        for (int e = e0; e < eC; ++e) {
            uint2 ed = eb[e];
            acc += ts[ed.x * 64 + j] * __uint_as_float(ed.y);
        }
        for (int e = e0 > ECAP ? e0 : ECAP; e < e1; ++e) {
            uint2 ed = eg[e];
            acc += ts[ed.x * 64 + j] * __uint_as_float(ed.y);
        }
        float u = fmaxf(acc + gb[j], 0.f);
        float mean = wave_sum64(u) * (1.f / 64.f);
        float dv = u - mean;
        float var = wave_sum64(dv * dv) * (1.f / 64.f);
        hout[(g * NPG + i) * 64 + j] = dv * rsqrtf(var + 1e-5f) * lng[j] + lnb[j];
    }
}

// layer 3 (two 64-wide halves) + fused mean readout + gb3 + PE, writes seqT[d][g]
__global__ __launch_bounds__(256) void k_gcn3(
    const float* __restrict__ tg_all, const int* __restrict__ cnt,
    const int* __restrict__ node_off, const uint2* __restrict__ epackN,
    const float* __restrict__ b3, float* __restrict__ seqT) {
    int g = blockIdx.x >> 1, sl = blockIdx.x & 1;
    __shared__ float ts[NPG * 64];
    __shared__ float dinv2[NPG];
    __shared__ int noff[NPG + 1];
    __shared__ uint2 eb[ECAP];
    __shared__ float red[4][64];
    int tid = threadIdx.x, j = tid & 63, wid = tid >> 6;
    const float* tg = tg_all + (size_t)g * NPG * DD + sl * 64;
    for (int idx = tid; idx < NPG * 16; idx += 256) {
        int i = idx >> 4, c = idx & 15;
        ((float4*)ts)[idx] = ((const float4*)(tg + i * DD))[c];
    }
    for (int i = tid; i <= NPG; i += 256) noff[i] = node_off[g * NPG + i];
    for (int i = tid; i < NPG; i += 256) dinv2[i] = 1.f / (float)(cnt[g * NPG + i] + 1);
    __syncthreads();
    int ebase = noff[0];
    int ecnt = noff[NPG] - ebase;
    const uint2* eg = epackN + ebase;
    int ecap = ecnt < ECAP ? ecnt : ECAP;
    for (int i = tid; i < ecap; i += 256) eb[i] = eg[i];
    __syncthreads();
    float rsum = 0.f;
    for (int i = wid; i < NPG; i += 4) {
        float acc = ts[i * 64 + j] * dinv2[i];
        int e0 = noff[i] - ebase, e1 = noff[i + 1] - ebase;
        int eC = e1 < ECAP ? e1 : ECAP;
        for (int e = e0; e < eC; ++e) {
            uint2 ed = eb[e];
            acc += ts[ed.x * 64 + j] * __uint_as_float(ed.y);
        }
        for (int e = e0 > ECAP ? e0 : ECAP; e < e1; ++e) {
            uint2 ed = eg[e];
            acc += ts[ed.x * 64 + j] * __uint_as_float(ed.y);
        }
        rsum += acc;
    }
    red[wid][j] = rsum;
    __syncthreads();
    if (tid < 64) {
        int d = sl * 64 + j;
        float val = (red[0][j] + red[1][j] + red[2][j] + red[3][j]) * (1.f / NPG) + b3[d];
        float freq = expf((float)(d & ~1) * (-9.210340371976184f / 128.f));
        float ang = (float)(g & (TT - 1)) * freq;
        val += (d & 1) ? cosf(ang) : sinf(ang);
        seqT[d * GG + g] = val;
    }
}

// dense per-node transform (row-major in/out)
template <int IN, int OUT>
__global__ void k_lin(const float* __restrict__ in, const float* __restrict__ W,
                      float* __restrict__ out) {
    int idx = blockIdx.x * blockDim.x + threadIdx.x;
    int n = idx / OUT, j = idx % OUT;
    if (n >= NN) return;
    const float* row = in + (long)n * IN;
    float acc = 0.f;
#pragma unroll 8
    for (int i = 0; i < IN; i++) acc += row[i] * W[i * OUT + j];
    out[idx] = acc;
}

// ---------------- Transformer (transposed activations: [feat][512]) ----------------

template <int K, bool RELU, bool RES>
__global__ __launch_bounds__(128) void k_gemmT(
    const float* __restrict__ AT, const float* __restrict__ W,
    const float* __restrict__ bias, const float* __restrict__ resP,
    float* __restrict__ C) {
    int o = blockIdx.x, t = threadIdx.x;
    __shared__ float ws[K];
    for (int k = t; k < K; k += 128) ws[k] = W[o * K + k];
    __syncthreads();
    const float4* A4 = (const float4*)AT;
    float4 acc = make_float4(0.f, 0.f, 0.f, 0.f);
#pragma unroll 8
    for (int k = 0; k < K; ++k) {
        float w = ws[k];
        float4 a = A4[k * 128 + t];
        acc.x += a.x * w; acc.y += a.y * w; acc.z += a.z * w; acc.w += a.w * w;
    }
    float bv = bias[o];
    acc.x += bv; acc.y += bv; acc.z += bv; acc.w += bv;
    if (RELU) {
        acc.x = fmaxf(acc.x, 0.f); acc.y = fmaxf(acc.y, 0.f);
        acc.z = fmaxf(acc.z, 0.f); acc.w = fmaxf(acc.w, 0.f);
    }
    if (RES) {
        float4 r = ((const float4*)resP)[o * 128 + t];
        acc.x += r.x; acc.y += r.y; acc.z += r.z; acc.w += r.w;
    }
    ((float4*)C)[o * 128 + t] = acc;
}

__global__ __launch_bounds__(64) void k_attnT(const float* __restrict__ qkvT,
                                              float* __restrict__ aT) {
    int b = blockIdx.x >> 2, h = blockIdx.x & 3;
    int t = threadIdx.x;
    __shared__ float Ks[32][TT], Vs[32][TT];
    __shared__ float sp[TT][TT + 1];
    int col = b * TT + t;
#pragma unroll
    for (int dh = 0; dh < 32; ++dh) {
        Ks[dh][t] = qkvT[(DD + h * 32 + dh) * GG + col];
        Vs[dh][t] = qkvT[(2 * DD + h * 32 + dh) * GG + col];
    }
    float q[32];
#pragma unroll
    for (int dh = 0; dh < 32; ++dh) q[dh] = qkvT[(h * 32 + dh) * GG + col];
    __syncthreads();
    const float scale = 0.17677669529663687f;  // 1/sqrt(32)
    for (int jj = 0; jj < TT; ++jj) {
        float a = 0.f;
#pragma unroll
        for (int dh = 0; dh < 32; ++dh) a += q[dh] * Ks[dh][jj];
        sp[t][jj] = a * scale;
    }
    float mx = -1e30f;
    for (int jj = 0; jj < TT; ++jj) mx = fmaxf(mx, sp[t][jj]);
    float ssum = 0.f;
    for (int jj = 0; jj < TT; ++jj) {
        float e2 = expf(sp[t][jj] - mx);
        sp[t][jj] = e2;
        ssum += e2;
    }
    float inv = 1.f / ssum;
    float o[32];
#pragma unroll
    for (int dh = 0; dh < 32; ++dh) o[dh] = 0.f;
    for (int jj = 0; jj < TT; ++jj) {
        float s = sp[t][jj] * inv;
#pragma unroll
        for (int dh = 0; dh < 32; ++dh) o[dh] += s * Vs[dh][jj];
    }
#pragma unroll
    for (int dh = 0; dh < 32; ++dh) aT[(h * 32 + dh) * GG + col] = o[dh];
}

__global__ void k_lnT(float* __restrict__ S, const float* __restrict__ g,
                      const float* __restrict__ bl) {
    int r = blockIdx.x * blockDim.x + threadIdx.x;  // 512 lanes, one per row
    float sum = 0.f, sq = 0.f;
    for (int d = 0; d < DD; ++d) {
        float v = S[d * GG + r];
        sum += v;
        sq += v * v;
    }
    float mean = sum * (1.f / DD);
    float var = sq * (1.f / DD) - mean * mean;
    float rstd = rsqrtf(var + 1e-5f);
    for (int d = 0; d < DD; ++d) {
        float v = S[d * GG + r];
        S[d * GG + r] = (v - mean) * rstd * g[d] + bl[d];
    }
}

__global__ __launch_bounds__(128) void k_headT(
    const float* __restrict__ seqT, const float* __restrict__ W1,
    const float* __restrict__ b1, const float* __restrict__ W2,
    const float* __restrict__ b2, float* __restrict__ out) {
    int b = blockIdx.x, t = threadIdx.x;
    __shared__ float pooled[DD];
    __shared__ float hid[64];
    const float4* row = (const float4*)(seqT + t * GG + b * TT);
    float4 s4 = make_float4(0.f, 0.f, 0.f, 0.f);
#pragma unroll
    for (int i = 0; i < 16; ++i) {
        float4 v = row[i];
        s4.x += v.x; s4.y += v.y; s4.z += v.z; s4.w += v.w;
    }
    pooled[t] = (s4.x + s4.y + s4.z + s4.w) * (1.f / TT);
    __syncthreads();
    if (t < 64) {
        float a = b1[t];
        const float* wr = W1 + t * DD;
        for (int k = 0; k < DD; ++k) a += pooled[k] * wr[k];
        hid[t] = fmaxf(a, 0.f);
    }
    __syncthreads();
    if (t < 2) {
        float a = b2[t];
        const float* wr = W2 + t * 64;
        for (int k = 0; k < 64; ++k) a += hid[k] * wr[k];
        out[b * 2 + t] = a;
    }
}

// ---------------- host ----------------

extern "C" void kernel_launch(void* const* d_in, const int* in_sizes, int n_in,
                              void* d_out, int out_size, void* d_ws, size_t ws_size,
                              hipStream_t stream) {
    const float* x     = (const float*)d_in[0];
    const int*   esrc  = (const int*)d_in[1];
    const int*   edst  = (const int*)d_in[2];
    const float* gW1   = (const float*)d_in[4];
    const float* gb1   = (const float*)d_in[5];
    const float* ln1g  = (const float*)d_in[6];
    const float* ln1b  = (const float*)d_in[7];
    const float* gW2   = (const float*)d_in[8];
    const float* gb2   = (const float*)d_in[9];
    const float* ln2g  = (const float*)d_in[10];
    const float* ln2b  = (const float*)d_in[11];
    const float* gW3   = (const float*)d_in[12];
    const float* gb3   = (const float*)d_in[13];
    const float* tWqkv = (const float*)d_in[14];
    const float* tbqkv = (const float*)d_in[15];
    const float* tWo   = (const float*)d_in[16];
    const float* tbo   = (const float*)d_in[17];
    const float* tg1   = (const float*)d_in[18];
    const float* tb1   = (const float*)d_in[19];
    const float* tg2   = (const float*)d_in[20];
    const float* tb2   = (const float*)d_in[21];
    const float* tWf1  = (const float*)d_in[22];
    const float* tbf1  = (const float*)d_in[23];
    const float* tWf2  = (const float*)d_in[24];
    const float* tbf2  = (const float*)d_in[25];
    const float* hW1   = (const float*)d_in[26];
    const float* hb1   = (const float*)d_in[27];
    const float* hW2   = (const float*)d_in[28];
    const float* hb2   = (const float*)d_in[29];
    float* out = (float*)d_out;

    int* cntN     = (int*)d_ws;              // NN
    int* gcnt     = cntN + NN;               // 512
    int* gbase    = gcnt + GG;               // 513 (pad 516)
    int* node_off = gbase + 516;             // NN+1 (pad NN+4)
    int* cursorN  = node_off + NN + 4;       // NN
    uint2* epackN = (uint2*)(cursorN + NN);  // EE
    float* bufA = (float*)(epackN + EE);     // NN*64
    float* bufB = bufA + (size_t)NN * 64;    // NN*128
    float* seqT = bufB + (size_t)NN * 128;   // 128*512
    float* qkvT = seqT + DD * GG;            // 384*512
    float* aT   = qkvT + 3 * DD * GG;        // 128*512
    float* f1T  = aT + DD * GG;              // 512*512

    const int BS = 256;
    // CSR build
    hipMemsetAsync(cntN, 0, NN * sizeof(int), stream);
    k_ncount<<<EE / BS, BS, 0, stream>>>(edst, cntN);
    k_gsum<<<GG, 64, 0, stream>>>(cntN, gcnt);
    k_gprefix<<<1, GG, 0, stream>>>(gcnt, gbase);
    k_nscan<<<GG, BS, 0, stream>>>(cntN, gbase, node_off, cursorN);
    k_escatter<<<EE / BS, BS, 0, stream>>>(esrc, edst, cntN, cursorN, epackN);

    // GCN
    k_gcn1<<<GG, BS, 0, stream>>>(x, gW1, cntN, node_off, epackN, gb1, ln1g, ln1b, bufA);
    k_lin<64, 64><<<(NN * 64) / BS, BS, 0, stream>>>(bufA, gW2, bufB);
    k_gcn2<<<GG, BS, 0, stream>>>(bufB, cntN, node_off, epackN, gb2, ln2g, ln2b, bufA);
    k_lin<64, 128><<<(NN * 128) / BS, BS, 0, stream>>>(bufA, gW3, bufB);
    k_gcn3<<<GG * 2, BS, 0, stream>>>(bufB, cntN, node_off, epackN, gb3, seqT);

    // Transformer (transposed activations)
    for (int l = 0; l < LL; l++) {
        k_gemmT<128, false, false><<<384, 128, 0, stream>>>(
            seqT, tWqkv + (size_t)l * 384 * 128, tbqkv + l * 384, nullptr, qkvT);
        k_attnT<<<BB * 4, TT, 0, stream>>>(qkvT, aT);
        k_gemmT<128, false, true><<<128, 128, 0, stream>>>(
            aT, tWo + (size_t)l * 128 * 128, tbo + l * 128, seqT, seqT);
        k_lnT<<<2, 256, 0, stream>>>(seqT, tg1 + l * 128, tb1 + l * 128);
        k_gemmT<128, true, false><<<512, 128, 0, stream>>>(
            seqT, tWf1 + (size_t)l * 512 * 128, tbf1 + l * 512, nullptr, f1T);
        k_gemmT<512, false, true><<<128, 128, 0, stream>>>(
            f1T, tWf2 + (size_t)l * 128 * 512, tbf2 + l * 128, seqT, seqT);
        k_lnT<<<2, 256, 0, stream>>>(seqT, tg2 + l * 128, tb2 + l * 128);
    }

    // head
    k_headT<<<BB, 128, 0, stream>>>(seqT, hW1, hb1, hW2, hb2, out);
}